// Round 7
// baseline (254.282 us; speedup 1.0000x reference)
//
#include <hip/hip_runtime.h>
#include <hip/hip_bf16.h>

// Problem constants (reference: B,K,N,F,H = 20000,10,100000,256,128)
constexpr int B_ = 20000;
constexpr int K_ = 10;
constexpr int N_ = 100000;
constexpr int F_ = 256;
constexpr int H_ = 128;
constexpr int RW = 3 * H_;  // interleaved qkv row width (384 ushorts = 768 B)

typedef __attribute__((ext_vector_type(8))) short bf16x8;
typedef __attribute__((ext_vector_type(4))) float f32x4;
typedef __attribute__((ext_vector_type(4))) unsigned short ushort4v;

__device__ __forceinline__ unsigned short f2bf(float x) {
  unsigned int u = __builtin_bit_cast(unsigned int, x);
  unsigned int r = u + 0x7fffu + ((u >> 16) & 1u);
  return (unsigned short)(r >> 16);
}

__device__ __forceinline__ float bf2f(unsigned int u16) {
  return __builtin_bit_cast(float, u16 << 16);
}

__device__ __forceinline__ float fast_tanh(float x) {
  float e = __expf(2.0f * x);
  return 1.0f - 2.0f * __builtin_amdgcn_rcpf(e + 1.0f);
}

// ---------------------------------------------------------------------------
// Prep: weights -> fragment-major bf16 layout (verified R5/R6).
// wat2 chunks (p, ks∈8, c∈8), 512 bf16 each: elem(lane,j) = Wa_p[32ks+8(lane>>4)+j][16c+(lane&15)]
// wbt2 chunks (p, c2∈8, ks2∈4):              elem(lane,j) = Wb_p[32ks2+8(lane>>4)+j][16c2+(lane&15)]
// ---------------------------------------------------------------------------
__global__ __launch_bounds__(256) void prep_kernel(
    const float* __restrict__ W1a, const float* __restrict__ W1b,
    const float* __restrict__ W2a, const float* __restrict__ W2b,
    const float* __restrict__ W3a, const float* __restrict__ W3b,
    unsigned short* __restrict__ wat2, unsigned short* __restrict__ wbt2) {
  const float* Wa[3] = {W1a, W2a, W3a};
  const float* Wb[3] = {W1b, W2b, W3b};
  int g = blockIdx.x * 256 + threadIdx.x;
  if (g < 3 * 64 * 512) {
    int chunk = g >> 9;
    int e = g & 511;
    int lane = e >> 3, j = e & 7;
    int c = chunk & 7;
    int ks = (chunk >> 3) & 7;
    int p = chunk >> 6;
    int k = 32 * ks + 8 * (lane >> 4) + j;
    int h = 16 * c + (lane & 15);
    wat2[g] = f2bf(Wa[p][k * H_ + h]);
  } else {
    int g2 = g - 3 * 64 * 512;
    int chunk = g2 >> 9;
    int e = g2 & 511;
    int lane = e >> 3, j = e & 7;
    int ks2 = chunk & 3;
    int c2 = (chunk >> 2) & 7;
    int p = chunk >> 5;
    int k = 32 * ks2 + 8 * (lane >> 4) + j;
    int h2 = 16 * c2 + (lane & 15);
    wbt2[g2] = f2bf(Wb[p][k * H_ + h2]);
  }
}

// ---------------------------------------------------------------------------
// Projections, transposed compute, ONE projection per block (blockIdx.y = p):
//   U^T = Wa_p^T (A, frag-major global) x X^T (B, LDS b128)
//   tanh -> ts[node][h] 8B LDS writes (C->A transpose bounce)
//   qkv_p^T = Wb_p^T x T^T, packed 8B stores into interleaved qkvI.
// Block 256 thr / 4 waves, MT=32 nodes (N_%32==0: no bounds checks).
// LDS 25.6 KB -> 6 blocks/CU; only 2 barriers per block.
// ---------------------------------------------------------------------------
constexpr int MT = 32;
constexpr int XS = F_ + 8;  // 264 shorts = 528 B row stride
constexpr int TS = H_ + 8;  // 136 shorts = 272 B row stride

__global__ __launch_bounds__(256, 4) void proj_kernel(
    const float* __restrict__ E,
    const unsigned short* __restrict__ wat2,
    const unsigned short* __restrict__ wbt2,
    unsigned short* __restrict__ qkvI) {
  __shared__ unsigned short xs[MT * XS];  // 16.9 KB
  __shared__ unsigned short ts[MT * TS];  // 8.7 KB

  const int tid = threadIdx.x;
  const int lane = tid & 63;
  const int w = tid >> 6;
  const int l15 = lane & 15;
  const int q = lane >> 4;
  const int row0 = blockIdx.x * MT;
  const int p = blockIdx.y;

  const unsigned short* __restrict__ wa = wat2 + p * (64 * 512);
  const unsigned short* __restrict__ wb = wbt2 + p * (32 * 512);

  // ---- stage X tile (fp32 -> bf16), coalesced dwordx4
  {
    const float4* Eg = (const float4*)E;
#pragma unroll
    for (int it = 0; it < 8; ++it) {
      int i = tid + 256 * it;
      int r = i >> 6;
      int c4 = i & 63;
      float4 v = Eg[(size_t)(row0 + r) * (F_ / 4) + c4];
      ushort4v o;
      o.x = f2bf(v.x); o.y = f2bf(v.y); o.z = f2bf(v.z); o.w = f2bf(v.w);
      *(ushort4v*)&xs[r * XS + c4 * 4] = o;
    }
  }
  __syncthreads();

  // ---- layer 1: U^T tiles, K=256. acc[i][nt]: h-tile 2w+i, node-tile nt.
  f32x4 acc[2][2];
#pragma unroll
  for (int i = 0; i < 2; ++i)
#pragma unroll
    for (int nt = 0; nt < 2; ++nt) acc[i][nt] = (f32x4)0.0f;

#pragma unroll
  for (int ks = 0; ks < 8; ++ks) {
    bf16x8 af0 = *(const bf16x8*)&wa[(ks * 8 + 2 * w) * 512 + lane * 8];
    bf16x8 af1 = *(const bf16x8*)&wa[(ks * 8 + 2 * w + 1) * 512 + lane * 8];
#pragma unroll
    for (int nt = 0; nt < 2; ++nt) {
      bf16x8 bx = *(const bf16x8*)&xs[(16 * nt + l15) * XS + 32 * ks + 8 * q];
      acc[0][nt] = __builtin_amdgcn_mfma_f32_16x16x32_bf16(af0, bx, acc[0][nt], 0, 0, 0);
      acc[1][nt] = __builtin_amdgcn_mfma_f32_16x16x32_bf16(af1, bx, acc[1][nt], 0, 0, 0);
    }
  }

  // ---- tanh + pack -> ts[node][h] via 8B LDS writes (C->A transpose)
#pragma unroll
  for (int i = 0; i < 2; ++i)
#pragma unroll
    for (int nt = 0; nt < 2; ++nt) {
      ushort4v o;
      o.x = f2bf(fast_tanh(acc[i][nt][0]));
      o.y = f2bf(fast_tanh(acc[i][nt][1]));
      o.z = f2bf(fast_tanh(acc[i][nt][2]));
      o.w = f2bf(fast_tanh(acc[i][nt][3]));
      // value (h = 16*(2w+i)+4q+r, node = 16nt+l15)
      *(ushort4v*)&ts[(16 * nt + l15) * TS + 16 * (2 * w + i) + 4 * q] = o;
    }
  __syncthreads();

  // ---- layer 2: qkv^T tiles, K=128
  f32x4 ac2[2][2];
#pragma unroll
  for (int i = 0; i < 2; ++i)
#pragma unroll
    for (int nt = 0; nt < 2; ++nt) ac2[i][nt] = (f32x4)0.0f;

#pragma unroll
  for (int ks2 = 0; ks2 < 4; ++ks2) {
    bf16x8 af0 = *(const bf16x8*)&wb[((2 * w) * 4 + ks2) * 512 + lane * 8];
    bf16x8 af1 = *(const bf16x8*)&wb[((2 * w + 1) * 4 + ks2) * 512 + lane * 8];
#pragma unroll
    for (int nt = 0; nt < 2; ++nt) {
      bf16x8 bt = *(const bf16x8*)&ts[(16 * nt + l15) * TS + 32 * ks2 + 8 * q];
      ac2[0][nt] = __builtin_amdgcn_mfma_f32_16x16x32_bf16(af0, bt, ac2[0][nt], 0, 0, 0);
      ac2[1][nt] = __builtin_amdgcn_mfma_f32_16x16x32_bf16(af1, bt, ac2[1][nt], 0, 0, 0);
    }
  }

  // ---- store qkv^T: col=node, rows h2 consecutive -> 8B contiguous stores
#pragma unroll
  for (int i = 0; i < 2; ++i)
#pragma unroll
    for (int nt = 0; nt < 2; ++nt) {
      int n = row0 + 16 * nt + l15;
      ushort4v o;
      o.x = f2bf(ac2[i][nt][0]);
      o.y = f2bf(ac2[i][nt][1]);
      o.z = f2bf(ac2[i][nt][2]);
      o.w = f2bf(ac2[i][nt][3]);
      *(ushort4v*)&qkvI[(size_t)n * RW + p * H_ + 16 * (2 * w + i) + 4 * q] = o;
    }
}

// ---------------------------------------------------------------------------
// Phase 2: one WAVE per batch node, gathering from interleaved qkvI
// (768 B contiguous per neighbor). No LDS, no barriers. (Unchanged R5/R6.)
// ---------------------------------------------------------------------------
__global__ __launch_bounds__(256) void agg_kernel(
    const int* __restrict__ nbr,
    const unsigned short* __restrict__ qkvI,
    float* __restrict__ out) {
  const int lane = threadIdx.x & 63;
  const int wv = threadIdx.x >> 6;
  const int b = blockIdx.x * 4 + wv;
  const int l15 = lane & 15;
  const int kg = lane >> 4;

  const int ni = nbr[b * K_ + (l15 < K_ ? l15 : 0)];
  const size_t nbase = (size_t)ni * RW;

  // scores[i][j] = q_i . k_j
  f32x4 sc = (f32x4)0.0f;
#pragma unroll
  for (int k = 0; k < 4; ++k) {
    const int off = k * 32 + kg * 8;
    bf16x8 qf = *(const bf16x8*)&qkvI[nbase + off];
    bf16x8 kf = *(const bf16x8*)&qkvI[nbase + H_ + off];
    sc = __builtin_amdgcn_mfma_f32_16x16x32_bf16(qf, kf, sc, 0, 0, 0);
  }

  if (l15 >= K_) {
#pragma unroll
    for (int r = 0; r < 4; ++r) sc[r] = -3.0e38f;
  }

  float mx[4], e[4], sm[4];
#pragma unroll
  for (int r = 0; r < 4; ++r) mx[r] = sc[r];
#pragma unroll
  for (int st = 1; st < 16; st <<= 1)
#pragma unroll
    for (int r = 0; r < 4; ++r) mx[r] = fmaxf(mx[r], __shfl_xor(mx[r], st, 16));
#pragma unroll
  for (int r = 0; r < 4; ++r) { e[r] = __expf(sc[r] - mx[r]); sm[r] = e[r]; }
#pragma unroll
  for (int st = 1; st < 16; st <<= 1)
#pragma unroll
    for (int r = 0; r < 4; ++r) sm[r] += __shfl_xor(sm[r], st, 16);

  float cs = 0.0f;
#pragma unroll
  for (int r = 0; r < 4; ++r) {
    float a = e[r] * __builtin_amdgcn_rcpf(sm[r]);
    if (kg * 4 + r >= K_) a = 0.0f;
    cs += a;
  }
  cs += __shfl_xor(cs, 16, 64);
  cs += __shfl_xor(cs, 32, 64);

  float o0 = 0.0f, o1 = 0.0f;
#pragma unroll
  for (int j = 0; j < K_; ++j) {
    const float cj = __shfl(cs, j, 64);
    const int nj = __shfl(ni, j, 64);
    const unsigned int v2 =
        *(const unsigned int*)&qkvI[(size_t)nj * RW + 2 * H_ + 2 * lane];
    o0 = fmaf(cj, bf2f(v2 & 0xffffu), o0);
    o1 = fmaf(cj, bf2f(v2 >> 16), o1);
  }
  *(float2*)&out[(size_t)b * H_ + 2 * lane] = make_float2(o0, o1);
}

extern "C" void kernel_launch(void* const* d_in, const int* in_sizes, int n_in,
                              void* d_out, int out_size, void* d_ws, size_t ws_size,
                              hipStream_t stream) {
  const int* nbr = (const int*)d_in[0];
  const float* E = (const float*)d_in[1];
  const float* W1a = (const float*)d_in[2];
  const float* W1b = (const float*)d_in[3];
  const float* W2a = (const float*)d_in[4];
  const float* W2b = (const float*)d_in[5];
  const float* W3a = (const float*)d_in[6];
  const float* W3b = (const float*)d_in[7];
  float* out = (float*)d_out;

  // workspace: qkvI [N][384] bf16 interleaved = 76.8 MB, then frag-major weights
  unsigned short* qkvI = (unsigned short*)d_ws;
  unsigned short* wat2 = qkvI + (size_t)N_ * RW;
  unsigned short* wbt2 = wat2 + (size_t)3 * 64 * 512;

  prep_kernel<<<(3 * 64 * 512 + 3 * 32 * 512) / 256, 256, 0, stream>>>(
      W1a, W1b, W2a, W2b, W3a, W3b, wat2, wbt2);
  dim3 pgrid(N_ / MT, 3);  // 3125 x 3: blockIdx.y selects projection
  proj_kernel<<<pgrid, 256, 0, stream>>>(E, wat2, wbt2, qkvI);
  agg_kernel<<<B_ / 4, 256, 0, stream>>>(nbr, qkvI, out);
}